// Round 10
// baseline (398.307 us; speedup 1.0000x reference)
//
#include <hip/hip_runtime.h>
#include <math.h>

#define B_ 4
#define C_ 512
#define L_ 4096
#define H_ 8
#define DH_ 64
#define MLP_ 2048
#define BL_ (B_*L_)      // 16384
#define LK_ (L_+1)       // 4097

typedef _Float16 f16;
typedef _Float16 f16x8 __attribute__((ext_vector_type(8)));
typedef _Float16 f16x4 __attribute__((ext_vector_type(4)));
typedef float f32x4 __attribute__((ext_vector_type(4)));

// async global->LDS, 16B per lane (m97 pattern)
__device__ __forceinline__ void gl16(void* lds, const void* g) {
  __builtin_amdgcn_global_load_lds((const __attribute__((address_space(1))) void*)g,
                                   (__attribute__((address_space(3))) void*)lds,
                                   16, 0, 0);
}

__device__ __forceinline__ float frcp(float x) { return __builtin_amdgcn_rcpf(x); }

// ---------------------------------------------------------------- transposes
__global__ __launch_bounds__(256) void transpose_w5(const float* __restrict__ Wq,
                                                    const float* __restrict__ Wk,
                                                    const float* __restrict__ Wv,
                                                    const float* __restrict__ Wkq,
                                                    const float* __restrict__ Wkk,
                                                    f16* __restrict__ dst) {
  int z = blockIdx.z;
  const float* W = (z == 0) ? Wq : (z == 1) ? Wk : (z == 2) ? Wv : (z == 3) ? Wkq : Wkk;
  f16* Wt = dst + (size_t)z * C_ * C_;
  __shared__ float tile[32][33];
  int n0 = blockIdx.x * 32, k0 = blockIdx.y * 32;
  int tx = threadIdx.x & 31, ty = threadIdx.x >> 5;
#pragma unroll
  for (int i = 0; i < 4; ++i)
    tile[ty + i * 8][tx] = W[(size_t)(k0 + ty + i * 8) * C_ + n0 + tx];
  __syncthreads();
#pragma unroll
  for (int i = 0; i < 4; ++i)
    Wt[(size_t)(n0 + ty + i * 8) * C_ + k0 + tx] = (f16)tile[tx][ty + i * 8];
}

// W1 (512x2048) and W2 (2048x512) transposes in one z=2 launch.
__global__ __launch_bounds__(256) void transpose_w12(const float* __restrict__ W1,
                                                     const float* __restrict__ W2,
                                                     f16* __restrict__ W1T,
                                                     f16* __restrict__ W2T) {
  __shared__ float tile[32][33];
  int z = blockIdx.z;
  const float* W = z ? W2 : W1;
  f16* Wt = z ? W2T : W1T;
  int K = z ? MLP_ : C_;
  int N = z ? C_ : MLP_;
  int n0 = (z ? blockIdx.y : blockIdx.x) * 32;
  int k0 = (z ? blockIdx.x : blockIdx.y) * 32;
  int tx = threadIdx.x & 31, ty = threadIdx.x >> 5;
#pragma unroll
  for (int i = 0; i < 4; ++i)
    tile[ty + i * 8][tx] = W[(size_t)(k0 + ty + i * 8) * N + n0 + tx];
  __syncthreads();
#pragma unroll
  for (int i = 0; i < 4; ++i)
    Wt[(size_t)(n0 + ty + i * 8) * K + k0 + tx] = (f16)tile[tx][ty + i * 8];
}

__global__ __launch_bounds__(256) void transpose_x(const float* __restrict__ x,
                                                   f16* __restrict__ xf) {
  __shared__ float tile[32][33];
  int b = blockIdx.z;
  int l0 = blockIdx.x * 32, c0 = blockIdx.y * 32;
  int tx = threadIdx.x & 31, ty = threadIdx.x >> 5;
#pragma unroll
  for (int i = 0; i < 4; ++i)
    tile[ty + i * 8][tx] = x[((size_t)b * C_ + c0 + ty + i * 8) * L_ + l0 + tx];
  __syncthreads();
#pragma unroll
  for (int i = 0; i < 4; ++i)
    xf[((size_t)b * L_ + l0 + ty + i * 8) * C_ + c0 + tx] = (f16)tile[tx][ty + i * 8];
}

// ------------------------------------------------- pack small param vectors
__global__ __launch_bounds__(256) void pack_params(
    const float* bq, const float* bk, const float* bv,
    const float* gq, const float* gk, const float* gv,
    const float* betaq, const float* betak, const float* betav,
    const float* bkq, const float* bkk,
    float* bqkv, float* gqkv, float* betaqkv, float* bphi, float* pk0t) {
  int i = blockIdx.x * 256 + threadIdx.x;  // 0..1535
  int w = i >> 9, c = i & 511;
  bqkv[i]    = (w == 0 ? bq : (w == 1 ? bk : bv))[c];
  gqkv[i]    = (w == 0 ? gq : (w == 1 ? gk : gv))[c];
  betaqkv[i] = (w == 0 ? betaq : (w == 1 ? betak : betav))[c];
  if (i < 1024) bphi[i] = (i < 512) ? bkq[i] : bkk[i - 512];
  if (i < 512) pk0t[i] = tanhf(bkk[i]) + 1.f;   // zero-token phiK
}

// ---------------------------------------------------------------- fused QKV GEMM + LayerNorm
// Tile M=64 tokens x N=512 (full which-row), K=512. 512 thr = 8 waves; wave
// wv owns cols wv*64..+64 (acc[4][4], same fragment geometry + XOR swizzles
// as the proven gemm128s; sbuf 2-barrier loop). Epilogue: bias -> padded LDS
// [64][528] (pad 16 f16 => LN re-read is 2-way bank-aliased = free), full-row
// LN via 8-lane shfl reduce, direct write of Qh/Kh/Vh.
// Replaces gemm256<5> + threeway ln16 (saves the 96 MB tmpqkv roundtrip).
__global__ __launch_bounds__(512, 2) void gemmqkv_ln(const f16* __restrict__ A,
                                                     const f16* __restrict__ Wt,
                                                     const float* __restrict__ bqkv,
                                                     const float* __restrict__ gqkv,
                                                     const float* __restrict__ betaqkv,
                                                     f16* __restrict__ Y) {
  __shared__ f16 smem[36864];   // A[0,4096) + B[4096,36864) = 72 KB; epi: [64][528]=33792
  const int which = blockIdx.y;
  const f16* Bt = Wt + (size_t)which * C_ * C_;
  const int tid = threadIdx.x;
  const int lane = tid & 63, wv = tid >> 6;
  const int bm = blockIdx.x * 64;
  const int l15 = lane & 15, q = lane >> 4;

  const int srow = tid >> 3;            // 0..63
  const int schunk = (tid & 7) ^ (srow & 7);
  const f16* pa = A + (size_t)(bm + srow) * C_ + schunk * 8;
  const f16* pb = Bt + (size_t)srow * C_ + schunk * 8;   // + p*64 rows
  f16* la = smem + tid * 8;
  f16* lb = smem + 4096 + tid * 8;
  const int sw0 = (q ^ (lane & 7)) * 8;
  const int sw1 = ((4 + q) ^ (lane & 7)) * 8;

  f32x4 acc[4][4] = {};

  for (int k0 = 0; k0 < C_; k0 += 64) {
    __syncthreads();               // prev k-step's reads done
    gl16(la, pa + k0);             // A: 64 rows x 8 chunks = 512 slots, 1 inst
#pragma unroll
    for (int p = 0; p < 8; ++p)    // B: 512 rows x 8 chunks, inst p = rows p*64..
      gl16(lb + p * 4096, pb + (size_t)p * 64 * C_ + k0);
    __syncthreads();               // vmcnt(0) drain -> staged
#pragma unroll
    for (int ks = 0; ks < 2; ++ks) {
      const int sw = ks ? sw1 : sw0;
      f16x8 af[4], bf[4];
#pragma unroll
      for (int i = 0; i < 4; ++i)
        af[i] = *(const f16x8*)&smem[(i * 16 + l15) * 64 + sw];
#pragma unroll
      for (int j = 0; j < 4; ++j)
        bf[j] = *(const f16x8*)&smem[4096 + (wv * 64 + j * 16 + l15) * 64 + sw];
#pragma unroll
      for (int i = 0; i < 4; ++i)
#pragma unroll
        for (int j = 0; j < 4; ++j)
          acc[i][j] = __builtin_amdgcn_mfma_f32_16x16x32_f16(af[i], bf[j], acc[i][j], 0, 0, 0);
    }
  }

  // epilogue: bias -> padded LDS [64][528]
  __syncthreads();
#pragma unroll
  for (int j = 0; j < 4; ++j) {
    int lc = wv * 64 + j * 16 + l15;
    float bb = bqkv[which * C_ + lc];
#pragma unroll
    for (int i = 0; i < 4; ++i)
#pragma unroll
      for (int r = 0; r < 4; ++r) {
        int lr = i * 16 + q * 4 + r;
        smem[lr * 528 + lc] = (f16)(acc[i][j][r] + bb);
      }
  }
  __syncthreads();

  // LN over full 512-row; thread t: row t>>3, col-slots (k*8 + (t&7)), k<8
  {
    int r = tid >> 3, g = tid & 7;
    f16x8 vv[8];
    float s = 0.f, s2 = 0.f;
#pragma unroll
    for (int k = 0; k < 8; ++k) {
      vv[k] = *(const f16x8*)&smem[r * 528 + (k * 8 + g) * 8];
#pragma unroll
      for (int j = 0; j < 8; ++j) { float f = (float)vv[k][j]; s += f; s2 += f * f; }
    }
    s += __shfl_xor(s, 1); s += __shfl_xor(s, 2); s += __shfl_xor(s, 4);
    s2 += __shfl_xor(s2, 1); s2 += __shfl_xor(s2, 2); s2 += __shfl_xor(s2, 4);
    float mu = s * (1.f / C_);
    float rstd = rsqrtf(s2 * (1.f / C_) - mu * mu + 1e-5f);
    const float* gp = gqkv + which * C_;
    const float* bp = betaqkv + which * C_;
#pragma unroll
    for (int k = 0; k < 8; ++k) {
      int c0 = (k * 8 + g) * 8;
      f16x8 o;
#pragma unroll
      for (int j = 0; j < 8; ++j)
        o[j] = (f16)(((float)vv[k][j] - mu) * rstd * gp[c0 + j] + bp[c0 + j]);
      *(f16x8*)&Y[((size_t)which * BL_ + bm + r) * C_ + c0] = o;
    }
  }
}

// ---------------------------------------------------------------- GEMM 128x128 single-buffer (m97 structure)
// round-7 A/B winner for high-grid GEMMs. EPI: 1 tanh(v)+1   2 gelu
template <int EPI>
__global__ __launch_bounds__(256, 4) void gemm128s(const f16* __restrict__ A,
                                                   const f16* __restrict__ Bt,
                                                   const float* __restrict__ bias,
                                                   f16* __restrict__ Ch,
                                                   int N, int K,
                                                   long long zA, long long zB,
                                                   long long zC, long long zBias) {
  __shared__ f16 smem[16384];  // 32 KB
  A  += (size_t)blockIdx.z * zA;
  Bt += (size_t)blockIdx.z * zB;
  Ch += (size_t)blockIdx.z * zC;
  bias += (size_t)blockIdx.z * zBias;

  const int tid = threadIdx.x;
  const int lane = tid & 63, wv = tid >> 6;
  const int wm = wv >> 1, wn = wv & 1;
  const int bm = blockIdx.y * 128, bn = blockIdx.x * 128;   // swapped roles
  const int l15 = lane & 15, q = lane >> 4;

  const int srow = tid >> 3;
  const int schunk = (tid & 7) ^ (srow & 7);
  const f16* pa = A + (size_t)(bm + srow) * K + schunk * 8;
  const f16* pb = Bt + (size_t)(bn + srow) * K + schunk * 8;
  f16* la = smem + tid * 8;
  f16* lb = smem + 8192 + tid * 8;
  const int sw0 = (q ^ (lane & 7)) * 8;
  const int sw1 = ((4 + q) ^ (lane & 7)) * 8;

  f32x4 acc[4][4] = {};

  for (int k0 = 0; k0 < K; k0 += 64) {
    __syncthreads();
#pragma unroll
    for (int p = 0; p < 4; ++p) gl16(la + p * 2048, pa + (size_t)p * 32 * K + k0);
#pragma unroll
    for (int p = 0; p < 4; ++p) gl16(lb + p * 2048, pb + (size_t)p * 32 * K + k0);
    __syncthreads();
#pragma unroll
    for (int ks = 0; ks < 2; ++ks) {
      const int sw = ks ? sw1 : sw0;
      f16x8 af[4], bf[4];
#pragma unroll
      for (int i = 0; i < 4; ++i)
        af[i] = *(const f16x8*)&smem[(wm * 64 + i * 16 + l15) * 64 + sw];
#pragma unroll
      for (int j = 0; j < 4; ++j)
        bf[j] = *(const f16x8*)&smem[8192 + (wn * 64 + j * 16 + l15) * 64 + sw];
#pragma unroll
      for (int i = 0; i < 4; ++i)
#pragma unroll
        for (int j = 0; j < 4; ++j)
          acc[i][j] = __builtin_amdgcn_mfma_f32_16x16x32_f16(af[i], bf[j], acc[i][j], 0, 0, 0);
    }
  }

  __syncthreads();
#pragma unroll
  for (int j = 0; j < 4; ++j) {
    int lc = wn * 64 + j * 16 + l15;
    float bb = bias[bn + lc];
#pragma unroll
    for (int i = 0; i < 4; ++i) {
#pragma unroll
      for (int r = 0; r < 4; ++r) {
        int lr = wm * 64 + i * 16 + q * 4 + r;
        float v = acc[i][j][r] + bb;
        if (EPI == 1) {
          v = 2.0f * frcp(1.0f + __expf(-2.0f * v));      // tanh(v)+1
        } else if (EPI == 2) {
          v = v * frcp(1.0f + __expf(-1.5957691f * (v + 0.044715f * v * v * v)));
        }
        smem[lr * 128 + ((((lc >> 3) ^ (lr & 15)) << 3) | (lc & 7))] = (f16)v;
      }
    }
  }
  __syncthreads();
#pragma unroll
  for (int p = 0; p < 8; ++p) {
    int idx = p * 256 + tid;
    int row = idx >> 4, ch = idx & 15;
    f16x8 vv = *(const f16x8*)&smem[row * 128 + ((ch ^ (row & 15)) << 3)];
    *(f16x8*)&Ch[(size_t)(bm + row) * N + bn + ch * 8] = vv;
  }
}

// ---------------------------------------------------------------- GEMM 128x128 dbuf, 512 threads (MLP-down)
__global__ __launch_bounds__(512, 2) void gemm512d6(const f16* __restrict__ A,
                                                    const f16* __restrict__ Bt,
                                                    const float* __restrict__ bias,
                                                    int N, int K,
                                                    const f16* __restrict__ Ares,
                                                    const float* __restrict__ Xres,
                                                    float* __restrict__ Fout) {
  __shared__ f16 smem[2 * 128 * 128];  // 64 KB
  const int tid = threadIdx.x;
  const int lane = tid & 63, wv = tid >> 6;      // 8 waves
  const int wm = wv >> 2, wn = wv & 3;           // 2 x 4
  const int bm = blockIdx.x * 128, bn = blockIdx.y * 128;
  const int l15 = lane & 15, q = lane >> 4;

  const int srow = tid >> 3;                     // 0..63
  const int schunk = (tid & 7) ^ (srow & 7);
  const f16* pa = A + (size_t)(bm + srow) * K + schunk * 8;
  const f16* pb = Bt + (size_t)(bn + srow) * K + schunk * 8;
  f16* la = smem + tid * 8;
  f16* lb = smem + 8192 + tid * 8;
  const int sw0 = (q ^ (lane & 7)) * 8;
  const int sw1 = ((4 + q) ^ (lane & 7)) * 8;

  f32x4 acc[4][2] = {};

#pragma unroll
  for (int p = 0; p < 2; ++p) gl16(la + p * 4096, pa + (size_t)p * 64 * K);
#pragma unroll
  for (int p = 0; p < 2; ++p) gl16(lb + p * 4096, pb + (size_t)p * 64 * K);

  int cur = 0;
  for (int k0 = 0; k0 < K; k0 += 64) {
    __syncthreads();
    const int nxt = cur ^ 1;
    if (k0 + 64 < K) {
#pragma unroll
      for (int p = 0; p < 2; ++p) gl16(la + nxt * 16384 + p * 4096, pa + (size_t)p * 64 * K + k0 + 64);
#pragma unroll
      for (int p = 0; p < 2; ++p) gl16(lb + nxt * 16384 + p * 4096, pb + (size_t)p * 64 * K + k0 + 64);
    }
    const f16* As = smem + cur * 16384;
    const f16* Bs = As + 8192;
#pragma unroll
    for (int ks = 0; ks < 2; ++ks) {
      const int sw = ks ? sw1 : sw0;
      f16x8 af[4], bf[2];
#pragma unroll
      for (int i = 0; i < 4; ++i)
        af[i] = *(const f16x8*)&As[(wm * 64 + i * 16 + l15) * 64 + sw];
#pragma unroll
      for (int j = 0; j < 2; ++j)
        bf[j] = *(const f16x8*)&Bs[(wn * 32 + j * 16 + l15) * 64 + sw];
#pragma unroll
      for (int i = 0; i < 4; ++i)
#pragma unroll
        for (int j = 0; j < 2; ++j)
          acc[i][j] = __builtin_amdgcn_mfma_f32_16x16x32_f16(af[i], bf[j], acc[i][j], 0, 0, 0);
    }
    cur = nxt;
  }

  __syncthreads();
#pragma unroll
  for (int j = 0; j < 2; ++j) {
    int lc = wn * 32 + j * 16 + l15;
    float bb = bias[bn + lc];
#pragma unroll
    for (int i = 0; i < 4; ++i) {
#pragma unroll
      for (int r = 0; r < 4; ++r) {
        int lr = wm * 64 + i * 16 + q * 4 + r;
        float v = acc[i][j][r] + bb;
        smem[lr * 128 + ((((lc >> 3) ^ (lr & 15)) << 3) | (lc & 7))] = (f16)v;
      }
    }
  }
  __syncthreads();
#pragma unroll
  for (int p = 0; p < 4; ++p) {
    int idx = p * 512 + tid;
    int row = idx >> 4, ch = idx & 15;
    f16x8 av = *(const f16x8*)&Ares[(size_t)(bm + row) * C_ + bn + ch * 8];
    f16* sp = &smem[row * 128 + ((ch ^ (row & 15)) << 3)];
    f16x8 sv = *(const f16x8*)sp;
#pragma unroll
    for (int jj = 0; jj < 8; ++jj) sv[jj] = (f16)((float)sv[jj] + (float)av[jj]);
    *(f16x8*)sp = sv;
  }
  __syncthreads();
  int c = tid & 127, lh = tid >> 7;              // lh 0..3
  int b = bm >> 12, lbase = (bm & 4095) + lh * 32;
  const float* xp = Xres + ((size_t)b * C_ + bn + c) * L_ + lbase;
  float* op = Fout + ((size_t)b * C_ + bn + c) * L_ + lbase;
  int chi = c >> 3, clo = c & 7;
#pragma unroll
  for (int s = 0; s < 8; ++s) {
    int l = lh * 32 + s * 4;
    float4 xv = *(const float4*)(xp + s * 4);
    float4 r;
    r.x = (float)smem[(l + 0) * 128 + (((chi ^ ((l + 0) & 15)) << 3) | clo)] + xv.x;
    r.y = (float)smem[(l + 1) * 128 + (((chi ^ ((l + 1) & 15)) << 3) | clo)] + xv.y;
    r.z = (float)smem[(l + 2) * 128 + (((chi ^ ((l + 2) & 15)) << 3) | clo)] + xv.z;
    r.w = (float)smem[(l + 3) * 128 + (((chi ^ ((l + 3) & 15)) << 3) | clo)] + xv.w;
    *(float4*)(op + s * 4) = r;
  }
}

// ---------------------------------------------------------------- kv via MFMA (round-9, verified)
__global__ __launch_bounds__(256, 2) void kv_mfma(const f16* __restrict__ phiK,
                                                  const f16* __restrict__ Vh,
                                                  const float* __restrict__ score,
                                                  float* __restrict__ kvp,
                                                  float* __restrict__ ksum) {
  __shared__ f16 Pt[4096];      // [d 64][l 64], swizzled slots
  __shared__ f16 Vt[4096];      // [e 64][l 64]
  __shared__ float red[16][64]; // ksum partial reduce
  const int bh = blockIdx.y, b = bh >> 3, h = bh & 7;
  const int l0 = blockIdx.x * 256;
  const int t = threadIdx.x, lane = t & 63, wv = t >> 6;
  const int wd = wv >> 1, we = wv & 1;
  const int l15 = lane & 15, q = lane >> 4;
  const int sw0 = (q ^ (lane & 7)) * 8;
  const int sw1 = ((4 + q) ^ (lane & 7)) * 8;
  const int lb = (t >> 4) * 4;          // l base within chunk (0..60)
  const int c4 = (t & 15) * 4;          // d/e base

  float ksacc[4] = {0.f, 0.f, 0.f, 0.f};
  f32x4 acc[2][2] = {};

  for (int cc = 0; cc < 4; ++cc) {
    __syncthreads();
    f16x4 pk4[4], vv4[4];
    float w4[4];
#pragma unroll
    for (int lp = 0; lp < 4; ++lp) {
      int lg = l0 + cc * 64 + lb + lp;
      size_t grow = ((size_t)b * L_ + lg) * C_ + h * DH_ + c4;
      pk4[lp] = *(const f16x4*)(phiK + grow);
      vv4[lp] = *(const f16x4*)(Vh + grow);
      w4[lp] = score[(size_t)bh * LK_ + 1 + lg];
    }
#pragma unroll
    for (int j = 0; j < 4; ++j) {
      int d = c4 + j;
      f16x4 pw, vw;
#pragma unroll
      for (int lp = 0; lp < 4; ++lp) {
        float wp = w4[lp] * (float)pk4[lp][j];
        ksacc[j] += wp;
        pw[lp] = (f16)wp;
        vw[lp] = vv4[lp][j];
      }
      int addr = d * 64 + ((((lb >> 3) ^ (d & 7)) << 3) | (lb & 7));
      *(f16x4*)&Pt[addr] = pw;
      *(f16x4*)&Vt[addr] = vw;
    }
    __syncthreads();
#pragma unroll
    for (int ks = 0; ks < 2; ++ks) {
      const int sw = ks ? sw1 : sw0;
      f16x8 af[2], bf[2];
#pragma unroll
      for (int i = 0; i < 2; ++i)
        af[i] = *(const f16x8*)&Pt[(wd * 32 + i * 16 + l15) * 64 + sw];
#pragma unroll
      for (int j = 0; j < 2; ++j)
        bf[j] = *(const f16x8*)&Vt[(we * 32 + j * 16 + l15) * 64 + sw];
#pragma unroll
      for (int i = 0; i < 2; ++i)
#pragma unroll
        for (int j = 0; j < 2; ++j)
          acc[i][j] = __builtin_amdgcn_mfma_f32_16x16x32_f16(af[i], bf[j], acc[i][j], 0, 0, 0);
    }
  }

  __syncthreads();
#pragma unroll
  for (int j = 0; j < 4; ++j) red[t >> 4][c4 + j] = ksacc[j];
  __syncthreads();
  if (t < 64) {
    float s = 0.f;
#pragma unroll
    for (int g = 0; g < 16; ++g) s += red[g][t];
    atomicAdd(&ksum[bh * 64 + t], s);
  }

  float* dst = kvp + ((size_t)bh * 16 + blockIdx.x) * 4096;
#pragma unroll
  for (int i = 0; i < 2; ++i)
#pragma unroll
    for (int j = 0; j < 2; ++j) {
      int d = wd * 32 + i * 16 + q * 4;
      int e = we * 32 + j * 16 + l15;
      *(f32x4*)&dst[e * 64 + d] = acc[i][j];
    }
}

// compact per-head kvT[b][h][e][d] (f16), summing 16 partials.
__global__ __launch_bounds__(256) void build_kvt(const float* __restrict__ kvp,
                                                 f16* __restrict__ kvt) {
  int i = blockIdx.x * 256 + threadIdx.x;
  int bh = i >> 12;
  const float* p = kvp + ((size_t)bh * 16) * 4096 + (i & 4095);
  float v = 0.f;
#pragma unroll
  for (int pp = 0; pp < 16; ++pp) v += p[pp * 4096];
  kvt[i] = (f16)v;
}

// ---------------------------------------------------------------- fused attention-out + bottom + LayerNorm
// Block = 64 tokens x all 8 heads (full 512 row). phiQ tile staged swizzled;
// kvt B-fragments loaded DIRECTLY from global (256 KB, L2-hot; fragment
// layout needs no swizzle: lane reads row j*16+l15, cols ks*32+q*8).
// Wave wv owns heads 2wv, 2wv+1 (acc[2][4][4]). bottom (incl. zero-token
// term) from staged A. Scale -> padded LDS [64][528] -> full-row LN -> ah.
// Replaces attn_out + ln16 (saves the 48 MB tmpA roundtrip).
__global__ __launch_bounds__(256, 2) void attn_ln(const f16* __restrict__ phiQ,
                                                  const f16* __restrict__ kvt,
                                                  const float* __restrict__ ksum,
                                                  const float* __restrict__ score,
                                                  const float* __restrict__ pk0t,
                                                  const float* __restrict__ g_at,
                                                  const float* __restrict__ b_at,
                                                  f16* __restrict__ Y) {
  __shared__ f16 smem[33792];       // staging: [64][512] linear; epi: [64][528]
  __shared__ float bots[512];       // [row 64][head 8]
  const int tid = threadIdx.x;
  const int lane = tid & 63, wv = tid >> 6;   // 4 waves
  const int bm = blockIdx.x * 64;
  const int b = bm >> 12;
  const int l15 = lane & 15, q = lane >> 4;

  // stage A = phiQ[bm..bm+64)[0..512): 4096 slots, 16 insts; swizzled source
#pragma unroll
  for (int p = 0; p < 16; ++p) {
    int slot = p * 256 + tid;
    int row = slot >> 6, c = slot & 63;
    int cg = (c & ~7) | ((c ^ row) & 7);
    gl16(smem + (size_t)slot * 8, phiQ + (size_t)(bm + row) * C_ + cg * 8);
  }
  __syncthreads();

  // bottom: thread t -> row r = t>>2, heads (t&3)*2, +1; ksum_eff incl s0*pk0
  {
    int r = tid >> 2, hp2 = (tid & 3) * 2;
#pragma unroll
    for (int hh = 0; hh < 2; ++hh) {
      int h = hp2 + hh;
      float s0 = score[(size_t)(b * H_ + h) * LK_];
      const float* ksh = ksum + (size_t)(b * H_ + h) * 64;
      const float* pkh = pk0t + h * 64;
      float bsum = 0.f;
#pragma unroll
      for (int cc = 0; cc < 8; ++cc) {
        int c = h * 8 + cc;
        int slot = (c & ~7) | ((c ^ r) & 7);
        f16x8 vv2 = *(const f16x8*)&smem[r * 512 + slot * 8];
#pragma unroll
        for (int j = 0; j < 8; ++j)
          bsum += (float)vv2[j] * (ksh[cc * 8 + j] + s0 * pkh[cc * 8 + j]);
      }
      bots[r * 8 + h] = bsum;
    }
  }

  // MFMA: per head, af from LDS, bf from global kvt
  f32x4 acc[2][4][4] = {};
#pragma unroll
  for (int hh = 0; hh < 2; ++hh) {
    int h = wv * 2 + hh;
    const f16* kb = kvt + (size_t)(b * H_ + h) * 4096;
#pragma unroll
    for (int ks = 0; ks < 2; ++ks) {
      const int sw = ((ks * 4 + q) ^ (l15 & 7)) * 8;
      f16x8 af[4], bf[4];
#pragma unroll
      for (int i = 0; i < 4; ++i)
        af[i] = *(const f16x8*)&smem[(i * 16 + l15) * 512 + h * 64 + sw];
#pragma unroll
      for (int j = 0; j < 4; ++j)
        bf[j] = *(const f16x8*)&kb[(j * 16 + l15) * 64 + ks * 32 + q * 8];
#pragma unroll
      for (int i = 0; i < 4; ++i)
#pragma unroll
        for (int j = 0; j < 4; ++j)
          acc[hh][i][j] = __builtin_amdgcn_mfma_f32_16x16x32_f16(af[i], bf[j], acc[hh][i][j], 0, 0, 0);
    }
  }
  __syncthreads();   // A reads done; bots visible

  // scale by 1/bottom -> padded LDS [64][528]
#pragma unroll
  for (int hh = 0; hh < 2; ++hh) {
    int h = wv * 2 + hh;
#pragma unroll
    for (int j = 0; j < 4; ++j) {
      int lc = h * 64 + j * 16 + l15;
#pragma unroll
      for (int i = 0; i < 4; ++i)
#pragma unroll
        for (int r = 0; r < 4; ++r) {
          int lr = i * 16 + q * 4 + r;
          float v = acc[hh][i][j][r] * frcp(bots[lr * 8 + h] + 1e-6f);
          smem[lr * 528 + lc] = (f16)v;
        }
    }
  }
  __syncthreads();

  // full-row LN + write; thread t: row t>>2, col-slots (k*4 + (t&3)), k<16
  {
    int r = tid >> 2, g = tid & 3;
    f16x8 vv[16];
    float s = 0.f, s2 = 0.f;
#pragma unroll
    for (int k = 0; k < 16; ++k) {
      vv[k] = *(const f16x8*)&smem[r * 528 + (k * 4 + g) * 8];
#pragma unroll
      for (int j = 0; j < 8; ++j) { float f = (float)vv[k][j]; s += f; s2 += f * f; }
    }
    s += __shfl_xor(s, 1); s += __shfl_xor(s, 2);
    s2 += __shfl_xor(s2, 1); s2 += __shfl_xor(s2, 2);
    float mu = s * (1.f / C_);
    float rstd = rsqrtf(s2 * (1.f / C_) - mu * mu + 1e-5f);
#pragma unroll
    for (int k = 0; k < 16; ++k) {
      int c0 = (k * 4 + g) * 8;
      f16x8 o;
#pragma unroll
      for (int j = 0; j < 8; ++j)
        o[j] = (f16)(((float)vv[k][j] - mu) * rstd * g_at[c0 + j] + b_at[c0 + j]);
      *(f16x8*)&Y[(size_t)(bm + r) * C_ + c0] = o;
    }
  }
}

// ---------------------------------------------------------------- q_probe
__global__ __launch_bounds__(256) void qprobe2(const f16* __restrict__ Q,
                                               float* __restrict__ qp) {
  int blk = blockIdx.x;
  int b = blk >> 6;
  int r0 = blk * 64;
  int t = threadIdx.x;
  int c8 = (t & 63) * 8, rg = t >> 6;
  float s[8] = {0.f, 0.f, 0.f, 0.f, 0.f, 0.f, 0.f, 0.f};
#pragma unroll
  for (int i = 0; i < 16; ++i) {
    const f16* row = Q + ((size_t)r0 + rg + i * 4) * C_ + c8;
    f16x8 v = *(const f16x8*)row;
#pragma unroll
    for (int j = 0; j < 8; ++j) s[j] += (float)v[j];
  }
  __shared__ float red[4][520];
#pragma unroll
  for (int j = 0; j < 8; ++j) red[rg][c8 + j] = s[j];
  __syncthreads();
  int c = t * 2;
  float a0 = red[0][c] + red[1][c] + red[2][c] + red[3][c];
  float a1 = red[0][c + 1] + red[1][c + 1] + red[2][c + 1] + red[3][c + 1];
  atomicAdd(&qp[b * C_ + c], a0);
  atomicAdd(&qp[b * C_ + c + 1], a1);
}

// ---------------------------------------------------------------- score logits
__global__ __launch_bounds__(256) void logits_kernel(const f16* __restrict__ Kh,
                                                     const float* __restrict__ qp,
                                                     float* __restrict__ score) {
  int wv = threadIdx.x >> 6, lane = threadIdx.x & 63;
  int token = blockIdx.x * 4 + wv;
  int b = token >> 12;
  int l = token & (L_ - 1);
  const f16* row = Kh + (size_t)token * C_;
  int h = lane >> 3, j0 = (lane & 7) * 8;
  const float* qph = qp + b * C_ + h * DH_ + j0;
  float p = 0.f;
#pragma unroll
  for (int j = 0; j < 8; ++j) p += qph[j] * (float)row[h * DH_ + j0 + j];
  p += __shfl_xor(p, 1); p += __shfl_xor(p, 2); p += __shfl_xor(p, 4);
  if ((lane & 7) == 0)
    score[((size_t)b * H_ + h) * LK_ + 1 + l] = p * (1.f / L_) * 0.125f;
}

__global__ __launch_bounds__(256) void softmax_kernel(float* __restrict__ score) {
  int bh = blockIdx.x, t = threadIdx.x;
  float* s = score + (size_t)bh * LK_;
  __shared__ float red[256];
  float mx = 0.f;
  for (int i = t; i < L_; i += 256) mx = fmaxf(mx, s[1 + i]);
  red[t] = mx; __syncthreads();
  for (int k = 128; k; k >>= 1) { if (t < k) red[t] = fmaxf(red[t], red[t + k]); __syncthreads(); }
  mx = red[0]; __syncthreads();
  float sum = (t == 0) ? expf(-mx) : 0.f;
  for (int i = t; i < L_; i += 256) { float e = expf(s[1 + i] - mx); s[1 + i] = e; sum += e; }
  red[t] = sum; __syncthreads();
  for (int k = 128; k; k >>= 1) { if (t < k) red[t] += red[t + k]; __syncthreads(); }
  float inv = 1.f / red[0];
  __syncthreads();
  for (int i = t; i < L_; i += 256) s[1 + i] *= inv;
  if (t == 0) s[0] = expf(-mx) * inv;
}

// ---------------------------------------------------------------- launch
extern "C" void kernel_launch(void* const* d_in, const int* in_sizes, int n_in,
                              void* d_out, int out_size, void* d_ws, size_t ws_size,
                              hipStream_t stream) {
  (void)in_sizes; (void)n_in; (void)out_size; (void)ws_size;
  const float* x     = (const float*)d_in[0];
  const float* Wq    = (const float*)d_in[1];
  const float* bq    = (const float*)d_in[2];
  const float* gq    = (const float*)d_in[3];
  const float* betaq = (const float*)d_in[4];
  const float* Wk    = (const float*)d_in[5];
  const float* bk    = (const float*)d_in[6];
  const float* gk    = (const float*)d_in[7];
  const float* betak = (const float*)d_in[8];
  const float* Wv    = (const float*)d_in[9];
  const float* bv    = (const float*)d_in[10];
  const float* gv    = (const float*)d_in[11];
  const float* betav = (const float*)d_in[12];
  const float* Wkq   = (const float*)d_in[13];
  const float* bkq   = (const float*)d_in[14];
  const float* Wkk   = (const float*)d_in[15];
  const float* bkk   = (const float*)d_in[16];
  const float* g_at  = (const float*)d_in[17];
  const float* b_at  = (const float*)d_in[18];
  const float* W1    = (const float*)d_in[19];
  const float* b1    = (const float*)d_in[20];
  const float* W2    = (const float*)d_in[21];
  const float* b2    = (const float*)d_in[22];
  float* out = (float*)d_out;

  char* ws = (char*)d_ws;
  size_t off = 0;
  auto alloc = [&](size_t bytes) -> void* {
    void* p = ws + off;
    off += (bytes + 255) & ~(size_t)255;
    return p;
  };
  f16* U1    = (f16*)alloc((size_t)BL_ * MLP_ * 2);       // 64 MB (h1)
  f16* QKVh  = (f16*)alloc((size_t)3 * BL_ * C_ * 2);     // 48 MB
  f16* phiQK = (f16*)alloc((size_t)2 * BL_ * C_ * 2);     // 32 MB
  f16* xf    = (f16*)alloc((size_t)BL_ * C_ * 2);         // 16 MB
  f16* WqkvT = (f16*)alloc((size_t)3 * C_ * C_ * 2);
  f16* WkqT  = (f16*)alloc((size_t)C_ * C_ * 2);
  f16* WkkT  = (f16*)alloc((size_t)C_ * C_ * 2);
  f16* W1T   = (f16*)alloc((size_t)C_ * MLP_ * 2);
  f16* W2T   = (f16*)alloc((size_t)MLP_ * C_ * 2);
  f16* kvt   = (f16*)alloc((size_t)B_ * H_ * DH_ * DH_ * 2);
  float* qp    = (float*)alloc((size_t)B_ * C_ * 4);          // \ one memset
  float* ksum  = (float*)alloc((size_t)B_ * H_ * DH_ * 4);    // / (adjacent)
  float* score = (float*)alloc((size_t)B_ * H_ * LK_ * 4);
  float* kvp   = (float*)alloc((size_t)B_ * H_ * 16 * 4096 * 4);
  float* bqkv    = (float*)alloc(1536 * 4);
  float* gqkv    = (float*)alloc(1536 * 4);
  float* betaqkv = (float*)alloc(1536 * 4);
  float* bphi    = (float*)alloc(1024 * 4);
  float* pk0t    = (float*)alloc(512 * 4);

  f16* h1 = U1;
  f16* Qh = QKVh;
  f16* Kh = QKVh + (size_t)BL_ * C_;
  f16* Vh = QKVh + (size_t)2 * BL_ * C_;
  f16* ah = QKVh;                    // reuse Qh region after attn
  f16* phiQ = phiQK;
  f16* phiK = phiQK + (size_t)BL_ * C_;

  dim3 blk(256);
  dim3 blk512(512);

  pack_params<<<6, blk, 0, stream>>>(bq, bk, bv, gq, gk, gv, betaq, betak, betav,
                                     bkq, bkk, bqkv, gqkv, betaqkv, bphi, pk0t);

  transpose_w5<<<dim3(16, 16, 5), blk, 0, stream>>>(Wq, Wk, Wv, Wkq, Wkk, WqkvT);
  transpose_w12<<<dim3(64, 16, 2), blk, 0, stream>>>(W1, W2, W1T, W2T);

  transpose_x<<<dim3(L_ / 32, C_ / 32, B_), blk, 0, stream>>>(x, xf);

  // fused QKV projection + threeway LN -> Qh/Kh/Vh directly
  gemmqkv_ln<<<dim3(BL_ / 64, 3), blk512, 0, stream>>>(
      xf, WqkvT, bqkv, gqkv, betaqkv, QKVh);

  // zero qp + ksum in one shot (adjacent allocations)
  hipMemsetAsync(qp, 0, (size_t)(B_ * C_ + B_ * H_ * DH_) * 4, stream);
  qprobe2<<<BL_ / 64, blk, 0, stream>>>(Qh, qp);

  // phi projections (m97-sbuf 128^2; grid = (N-tiles, M-tiles, z))
  gemm128s<1><<<dim3(C_ / 128, BL_ / 128, 2), blk, 0, stream>>>(
      Qh, WkqT, bphi, phiQ, C_, C_,
      (long long)BL_ * C_, (long long)C_ * C_, (long long)BL_ * C_, (long long)C_);

  logits_kernel<<<BL_ / 4, blk, 0, stream>>>(Kh, qp, score);
  softmax_kernel<<<B_ * H_, blk, 0, stream>>>(score);

  // kv partials + ksum via MFMA
  kv_mfma<<<dim3(16, B_ * H_), blk, 0, stream>>>(phiK, Vh, score, kvp, ksum);
  build_kvt<<<(B_ * H_ * DH_ * DH_) / 256, blk, 0, stream>>>(kvp, kvt);

  // fused attention-out + bottom + LN -> ah directly
  attn_ln<<<BL_ / 64, blk, 0, stream>>>(phiQ, kvt, ksum, score, pk0t, g_at, b_at, ah);

  // MLP up (m97-sbuf 128^2; grid = (N-tiles, M-tiles))
  gemm128s<2><<<dim3(MLP_ / 128, BL_ / 128), blk, 0, stream>>>(
      ah, W1T, b1, h1, MLP_, C_, 0, 0, 0, 0);
  // MLP down fused with residual-add + transpose + x-add -> out (512-thr dbuf)
  gemm512d6<<<dim3(BL_ / 128, C_ / 128), blk512, 0, stream>>>(
      h1, W2T, b2, C_, MLP_, ah, x, out);
}

// Round 11
// 389.402 us; speedup vs baseline: 1.0229x; 1.0229x over previous
//
#include <hip/hip_runtime.h>
#include <math.h>

#define B_ 4
#define C_ 512
#define L_ 4096
#define H_ 8
#define DH_ 64
#define MLP_ 2048
#define BL_ (B_*L_)      // 16384
#define LK_ (L_+1)       // 4097

typedef _Float16 f16;
typedef _Float16 f16x8 __attribute__((ext_vector_type(8)));
typedef _Float16 f16x4 __attribute__((ext_vector_type(4)));
typedef float f32x4 __attribute__((ext_vector_type(4)));

// async global->LDS, 16B per lane (m97 pattern)
__device__ __forceinline__ void gl16(void* lds, const void* g) {
  __builtin_amdgcn_global_load_lds((const __attribute__((address_space(1))) void*)g,
                                   (__attribute__((address_space(3))) void*)lds,
                                   16, 0, 0);
}

__device__ __forceinline__ float frcp(float x) { return __builtin_amdgcn_rcpf(x); }

// ---------------------------------------------------------------- transposes
__global__ __launch_bounds__(256) void transpose_w5(const float* __restrict__ Wq,
                                                    const float* __restrict__ Wk,
                                                    const float* __restrict__ Wv,
                                                    const float* __restrict__ Wkq,
                                                    const float* __restrict__ Wkk,
                                                    f16* __restrict__ dst) {
  int z = blockIdx.z;
  const float* W = (z == 0) ? Wq : (z == 1) ? Wk : (z == 2) ? Wv : (z == 3) ? Wkq : Wkk;
  f16* Wt = dst + (size_t)z * C_ * C_;
  __shared__ float tile[32][33];
  int n0 = blockIdx.x * 32, k0 = blockIdx.y * 32;
  int tx = threadIdx.x & 31, ty = threadIdx.x >> 5;
#pragma unroll
  for (int i = 0; i < 4; ++i)
    tile[ty + i * 8][tx] = W[(size_t)(k0 + ty + i * 8) * C_ + n0 + tx];
  __syncthreads();
#pragma unroll
  for (int i = 0; i < 4; ++i)
    Wt[(size_t)(n0 + ty + i * 8) * C_ + k0 + tx] = (f16)tile[tx][ty + i * 8];
}

// W1 (512x2048) and W2 (2048x512) transposes in one z=2 launch.
__global__ __launch_bounds__(256) void transpose_w12(const float* __restrict__ W1,
                                                     const float* __restrict__ W2,
                                                     f16* __restrict__ W1T,
                                                     f16* __restrict__ W2T) {
  __shared__ float tile[32][33];
  int z = blockIdx.z;
  const float* W = z ? W2 : W1;
  f16* Wt = z ? W2T : W1T;
  int K = z ? MLP_ : C_;
  int N = z ? C_ : MLP_;
  int n0 = (z ? blockIdx.y : blockIdx.x) * 32;
  int k0 = (z ? blockIdx.x : blockIdx.y) * 32;
  int tx = threadIdx.x & 31, ty = threadIdx.x >> 5;
#pragma unroll
  for (int i = 0; i < 4; ++i)
    tile[ty + i * 8][tx] = W[(size_t)(k0 + ty + i * 8) * N + n0 + tx];
  __syncthreads();
#pragma unroll
  for (int i = 0; i < 4; ++i)
    Wt[(size_t)(n0 + ty + i * 8) * K + k0 + tx] = (f16)tile[tx][ty + i * 8];
}

__global__ __launch_bounds__(256) void transpose_x(const float* __restrict__ x,
                                                   f16* __restrict__ xf) {
  __shared__ float tile[32][33];
  int b = blockIdx.z;
  int l0 = blockIdx.x * 32, c0 = blockIdx.y * 32;
  int tx = threadIdx.x & 31, ty = threadIdx.x >> 5;
#pragma unroll
  for (int i = 0; i < 4; ++i)
    tile[ty + i * 8][tx] = x[((size_t)b * C_ + c0 + ty + i * 8) * L_ + l0 + tx];
  __syncthreads();
#pragma unroll
  for (int i = 0; i < 4; ++i)
    xf[((size_t)b * L_ + l0 + ty + i * 8) * C_ + c0 + tx] = (f16)tile[tx][ty + i * 8];
}

// ------------------------------------------------- pack small param vectors
__global__ __launch_bounds__(256) void pack_params(
    const float* bq, const float* bk, const float* bv,
    const float* gq, const float* gk, const float* gv,
    const float* betaq, const float* betak, const float* betav,
    const float* bkq, const float* bkk,
    float* bqkv, float* gqkv, float* betaqkv, float* bphi, float* pk0t) {
  int i = blockIdx.x * 256 + threadIdx.x;  // 0..1535
  int w = i >> 9, c = i & 511;
  bqkv[i]    = (w == 0 ? bq : (w == 1 ? bk : bv))[c];
  gqkv[i]    = (w == 0 ? gq : (w == 1 ? gk : gv))[c];
  betaqkv[i] = (w == 0 ? betaq : (w == 1 ? betak : betav))[c];
  if (i < 1024) bphi[i] = (i < 512) ? bkq[i] : bkk[i - 512];
  if (i < 512) pk0t[i] = tanhf(bkk[i]) + 1.f;   // zero-token phiK
}

// ---------------------------------------------------------------- GEMM 128x128 single-buffer (m97 structure)
// round-7 A/B winner for high-grid GEMMs. EPI: 1 tanh(v)+1   2 gelu
template <int EPI>
__global__ __launch_bounds__(256, 4) void gemm128s(const f16* __restrict__ A,
                                                   const f16* __restrict__ Bt,
                                                   const float* __restrict__ bias,
                                                   f16* __restrict__ Ch,
                                                   int N, int K,
                                                   long long zA, long long zB,
                                                   long long zC, long long zBias) {
  __shared__ f16 smem[16384];  // 32 KB
  A  += (size_t)blockIdx.z * zA;
  Bt += (size_t)blockIdx.z * zB;
  Ch += (size_t)blockIdx.z * zC;
  bias += (size_t)blockIdx.z * zBias;

  const int tid = threadIdx.x;
  const int lane = tid & 63, wv = tid >> 6;
  const int wm = wv >> 1, wn = wv & 1;
  const int bm = blockIdx.y * 128, bn = blockIdx.x * 128;   // swapped roles
  const int l15 = lane & 15, q = lane >> 4;

  const int srow = tid >> 3;
  const int schunk = (tid & 7) ^ (srow & 7);
  const f16* pa = A + (size_t)(bm + srow) * K + schunk * 8;
  const f16* pb = Bt + (size_t)(bn + srow) * K + schunk * 8;
  f16* la = smem + tid * 8;
  f16* lb = smem + 8192 + tid * 8;
  const int sw0 = (q ^ (lane & 7)) * 8;
  const int sw1 = ((4 + q) ^ (lane & 7)) * 8;

  f32x4 acc[4][4] = {};

  for (int k0 = 0; k0 < K; k0 += 64) {
    __syncthreads();
#pragma unroll
    for (int p = 0; p < 4; ++p) gl16(la + p * 2048, pa + (size_t)p * 32 * K + k0);
#pragma unroll
    for (int p = 0; p < 4; ++p) gl16(lb + p * 2048, pb + (size_t)p * 32 * K + k0);
    __syncthreads();
#pragma unroll
    for (int ks = 0; ks < 2; ++ks) {
      const int sw = ks ? sw1 : sw0;
      f16x8 af[4], bf[4];
#pragma unroll
      for (int i = 0; i < 4; ++i)
        af[i] = *(const f16x8*)&smem[(wm * 64 + i * 16 + l15) * 64 + sw];
#pragma unroll
      for (int j = 0; j < 4; ++j)
        bf[j] = *(const f16x8*)&smem[8192 + (wn * 64 + j * 16 + l15) * 64 + sw];
#pragma unroll
      for (int i = 0; i < 4; ++i)
#pragma unroll
        for (int j = 0; j < 4; ++j)
          acc[i][j] = __builtin_amdgcn_mfma_f32_16x16x32_f16(af[i], bf[j], acc[i][j], 0, 0, 0);
    }
  }

  __syncthreads();
#pragma unroll
  for (int j = 0; j < 4; ++j) {
    int lc = wn * 64 + j * 16 + l15;
    float bb = bias[bn + lc];
#pragma unroll
    for (int i = 0; i < 4; ++i) {
#pragma unroll
      for (int r = 0; r < 4; ++r) {
        int lr = wm * 64 + i * 16 + q * 4 + r;
        float v = acc[i][j][r] + bb;
        if (EPI == 1) {
          v = 2.0f * frcp(1.0f + __expf(-2.0f * v));      // tanh(v)+1
        } else if (EPI == 2) {
          v = v * frcp(1.0f + __expf(-1.5957691f * (v + 0.044715f * v * v * v)));
        }
        smem[lr * 128 + ((((lc >> 3) ^ (lr & 15)) << 3) | (lc & 7))] = (f16)v;
      }
    }
  }
  __syncthreads();
#pragma unroll
  for (int p = 0; p < 8; ++p) {
    int idx = p * 256 + tid;
    int row = idx >> 4, ch = idx & 15;
    f16x8 vv = *(const f16x8*)&smem[row * 128 + ((ch ^ (row & 15)) << 3)];
    *(f16x8*)&Ch[(size_t)(bm + row) * N + bn + ch * 8] = vv;
  }
}

// ---------------------------------------------------------------- GEMM 256x256 (counted-vmcnt + setprio)
template <int EPI>
__global__ __launch_bounds__(512, 2) void gemm256(const f16* __restrict__ A,
                                                  const f16* __restrict__ Bt,
                                                  const float* __restrict__ bias,
                                                  f16* __restrict__ Ch,
                                                  int N, int K,
                                                  long long zA, long long zB,
                                                  long long zC, long long zBias) {
  __shared__ f16 smem[65536];  // 128 KB
  A  += (size_t)blockIdx.z * zA;
  Bt += (size_t)blockIdx.z * zB;
  Ch += (size_t)blockIdx.z * zC;
  bias += (size_t)blockIdx.z * zBias;

  const int tid = threadIdx.x;
  const int lane = tid & 63, wv = tid >> 6;
  const int wm = wv >> 2, wn = wv & 3;
  const int bm = blockIdx.x * 256, bn = blockIdx.y * 256;
  const int l15 = lane & 15, q = lane >> 4;

  const int srow = tid >> 3;
  const int schunk = (tid & 7) ^ (srow & 7);
  const f16* pa = A + (size_t)(bm + srow) * K + schunk * 8;
  const f16* pb = Bt + (size_t)(bn + srow) * K + schunk * 8;
  const int sw0 = (q ^ (lane & 7)) * 8;
  const int sw1 = ((4 + q) ^ (lane & 7)) * 8;
  const int NT = K >> 6;

  auto STAGE = [&](int t) {
    f16* bs = smem + (t & 1) * 32768;
    const f16* pat = pa + t * 64;
    const f16* pbt = pb + t * 64;
#pragma unroll
    for (int p = 0; p < 4; ++p) gl16(bs + p * 4096 + tid * 8, pat + (size_t)p * 64 * K);
#pragma unroll
    for (int p = 0; p < 4; ++p) gl16(bs + 16384 + p * 4096 + tid * 8, pbt + (size_t)p * 64 * K);
  };

  f32x4 acc[8][4] = {};

  STAGE(0);
  STAGE(1);

  for (int t = 0; t < NT; ++t) {
    if (t < NT - 1) asm volatile("s_waitcnt vmcnt(8)" ::: "memory");
    else            asm volatile("s_waitcnt vmcnt(0)" ::: "memory");
    __builtin_amdgcn_s_barrier();
    asm volatile("" ::: "memory");

    const f16* As = smem + (t & 1) * 32768;
    const f16* Bs = As + 16384;

    f16x8 bfr[4][2], afr[4][2];
#pragma unroll
    for (int n = 0; n < 4; ++n) {
      bfr[n][0] = *(const f16x8*)&Bs[(wn * 64 + n * 16 + l15) * 64 + sw0];
      bfr[n][1] = *(const f16x8*)&Bs[(wn * 64 + n * 16 + l15) * 64 + sw1];
    }
#pragma unroll
    for (int m = 0; m < 4; ++m) {
      afr[m][0] = *(const f16x8*)&As[(wm * 128 + m * 16 + l15) * 64 + sw0];
      afr[m][1] = *(const f16x8*)&As[(wm * 128 + m * 16 + l15) * 64 + sw1];
    }
    __builtin_amdgcn_s_setprio(1);
#pragma unroll
    for (int ks = 0; ks < 2; ++ks)
#pragma unroll
      for (int m = 0; m < 4; ++m)
#pragma unroll
        for (int n = 0; n < 4; ++n)
          acc[m][n] = __builtin_amdgcn_mfma_f32_16x16x32_f16(afr[m][ks], bfr[n][ks], acc[m][n], 0, 0, 0);
    __builtin_amdgcn_s_setprio(0);
#pragma unroll
    for (int m = 0; m < 4; ++m) {
      afr[m][0] = *(const f16x8*)&As[(wm * 128 + (m + 4) * 16 + l15) * 64 + sw0];
      afr[m][1] = *(const f16x8*)&As[(wm * 128 + (m + 4) * 16 + l15) * 64 + sw1];
    }
    asm volatile("s_waitcnt lgkmcnt(0)" ::: "memory");
    __builtin_amdgcn_s_barrier();
    asm volatile("" ::: "memory");
    if (t + 2 < NT) STAGE(t + 2);
    __builtin_amdgcn_s_setprio(1);
#pragma unroll
    for (int ks = 0; ks < 2; ++ks)
#pragma unroll
      for (int m = 0; m < 4; ++m)
#pragma unroll
        for (int n = 0; n < 4; ++n)
          acc[m + 4][n] = __builtin_amdgcn_mfma_f32_16x16x32_f16(afr[m][ks], bfr[n][ks], acc[m + 4][n], 0, 0, 0);
    __builtin_amdgcn_s_setprio(0);
  }

  __syncthreads();
#pragma unroll
  for (int n = 0; n < 4; ++n) {
    int lc = wn * 64 + n * 16 + l15;
    float bb = bias[bn + lc];
#pragma unroll
    for (int m = 0; m < 8; ++m) {
#pragma unroll
      for (int r = 0; r < 4; ++r) {
        int lr = wm * 128 + m * 16 + q * 4 + r;
        float v = acc[m][n][r] + bb;
        if (EPI == 1) {
          v = 2.0f * frcp(1.0f + __expf(-2.0f * v));
        } else if (EPI == 2) {
          v = v * frcp(1.0f + __expf(-1.5957691f * (v + 0.044715f * v * v * v)));
        }
        smem[lr * 256 + ((((lc >> 3) ^ (lr & 31)) << 3) | (lc & 7))] = (f16)v;
      }
    }
  }
  __syncthreads();
#pragma unroll
  for (int p = 0; p < 16; ++p) {
    int idx = p * 512 + tid;
    int row = idx >> 5, ch = idx & 31;
    f16x8 vv = *(const f16x8*)&smem[row * 256 + ((ch ^ (row & 31)) << 3)];
    *(f16x8*)&Ch[(size_t)(bm + row) * N + bn + ch * 8] = vv;
  }
}

// ---------------------------------------------------------------- GEMM 128x128 dbuf, 512 threads (MLP-down)
__global__ __launch_bounds__(512, 2) void gemm512d6(const f16* __restrict__ A,
                                                    const f16* __restrict__ Bt,
                                                    const float* __restrict__ bias,
                                                    int N, int K,
                                                    const f16* __restrict__ Ares,
                                                    const float* __restrict__ Xres,
                                                    float* __restrict__ Fout) {
  __shared__ f16 smem[2 * 128 * 128];  // 64 KB
  const int tid = threadIdx.x;
  const int lane = tid & 63, wv = tid >> 6;      // 8 waves
  const int wm = wv >> 2, wn = wv & 3;           // 2 x 4
  const int bm = blockIdx.x * 128, bn = blockIdx.y * 128;
  const int l15 = lane & 15, q = lane >> 4;

  const int srow = tid >> 3;                     // 0..63
  const int schunk = (tid & 7) ^ (srow & 7);
  const f16* pa = A + (size_t)(bm + srow) * K + schunk * 8;
  const f16* pb = Bt + (size_t)(bn + srow) * K + schunk * 8;
  f16* la = smem + tid * 8;
  f16* lb = smem + 8192 + tid * 8;
  const int sw0 = (q ^ (lane & 7)) * 8;
  const int sw1 = ((4 + q) ^ (lane & 7)) * 8;

  f32x4 acc[4][2] = {};

#pragma unroll
  for (int p = 0; p < 2; ++p) gl16(la + p * 4096, pa + (size_t)p * 64 * K);
#pragma unroll
  for (int p = 0; p < 2; ++p) gl16(lb + p * 4096, pb + (size_t)p * 64 * K);

  int cur = 0;
  for (int k0 = 0; k0 < K; k0 += 64) {
    __syncthreads();
    const int nxt = cur ^ 1;
    if (k0 + 64 < K) {
#pragma unroll
      for (int p = 0; p < 2; ++p) gl16(la + nxt * 16384 + p * 4096, pa + (size_t)p * 64 * K + k0 + 64);
#pragma unroll
      for (int p = 0; p < 2; ++p) gl16(lb + nxt * 16384 + p * 4096, pb + (size_t)p * 64 * K + k0 + 64);
    }
    const f16* As = smem + cur * 16384;
    const f16* Bs = As + 8192;
#pragma unroll
    for (int ks = 0; ks < 2; ++ks) {
      const int sw = ks ? sw1 : sw0;
      f16x8 af[4], bf[2];
#pragma unroll
      for (int i = 0; i < 4; ++i)
        af[i] = *(const f16x8*)&As[(wm * 64 + i * 16 + l15) * 64 + sw];
#pragma unroll
      for (int j = 0; j < 2; ++j)
        bf[j] = *(const f16x8*)&Bs[(wn * 32 + j * 16 + l15) * 64 + sw];
#pragma unroll
      for (int i = 0; i < 4; ++i)
#pragma unroll
        for (int j = 0; j < 2; ++j)
          acc[i][j] = __builtin_amdgcn_mfma_f32_16x16x32_f16(af[i], bf[j], acc[i][j], 0, 0, 0);
    }
    cur = nxt;
  }

  __syncthreads();
#pragma unroll
  for (int j = 0; j < 2; ++j) {
    int lc = wn * 32 + j * 16 + l15;
    float bb = bias[bn + lc];
#pragma unroll
    for (int i = 0; i < 4; ++i) {
#pragma unroll
      for (int r = 0; r < 4; ++r) {
        int lr = wm * 64 + i * 16 + q * 4 + r;
        float v = acc[i][j][r] + bb;
        smem[lr * 128 + ((((lc >> 3) ^ (lr & 15)) << 3) | (lc & 7))] = (f16)v;
      }
    }
  }
  __syncthreads();
#pragma unroll
  for (int p = 0; p < 4; ++p) {
    int idx = p * 512 + tid;
    int row = idx >> 4, ch = idx & 15;
    f16x8 av = *(const f16x8*)&Ares[(size_t)(bm + row) * C_ + bn + ch * 8];
    f16* sp = &smem[row * 128 + ((ch ^ (row & 15)) << 3)];
    f16x8 sv = *(const f16x8*)sp;
#pragma unroll
    for (int jj = 0; jj < 8; ++jj) sv[jj] = (f16)((float)sv[jj] + (float)av[jj]);
    *(f16x8*)sp = sv;
  }
  __syncthreads();
  int c = tid & 127, lh = tid >> 7;              // lh 0..3
  int b = bm >> 12, lbase = (bm & 4095) + lh * 32;
  const float* xp = Xres + ((size_t)b * C_ + bn + c) * L_ + lbase;
  float* op = Fout + ((size_t)b * C_ + bn + c) * L_ + lbase;
  int chi = c >> 3, clo = c & 7;
#pragma unroll
  for (int s = 0; s < 8; ++s) {
    int l = lh * 32 + s * 4;
    float4 xv = *(const float4*)(xp + s * 4);
    float4 r;
    r.x = (float)smem[(l + 0) * 128 + (((chi ^ ((l + 0) & 15)) << 3) | clo)] + xv.x;
    r.y = (float)smem[(l + 1) * 128 + (((chi ^ ((l + 1) & 15)) << 3) | clo)] + xv.y;
    r.z = (float)smem[(l + 2) * 128 + (((chi ^ ((l + 2) & 15)) << 3) | clo)] + xv.z;
    r.w = (float)smem[(l + 3) * 128 + (((chi ^ ((l + 3) & 15)) << 3) | clo)] + xv.w;
    *(float4*)(op + s * 4) = r;
  }
}

// ---------------------------------------------------------------- kv via MFMA (round-9, verified)
__global__ __launch_bounds__(256, 2) void kv_mfma(const f16* __restrict__ phiK,
                                                  const f16* __restrict__ Vh,
                                                  const float* __restrict__ score,
                                                  float* __restrict__ kvp,
                                                  float* __restrict__ ksum) {
  __shared__ f16 Pt[4096];      // [d 64][l 64], swizzled slots
  __shared__ f16 Vt[4096];      // [e 64][l 64]
  __shared__ float red[16][64]; // ksum partial reduce
  const int bh = blockIdx.y, b = bh >> 3, h = bh & 7;
  const int l0 = blockIdx.x * 256;
  const int t = threadIdx.x, lane = t & 63, wv = t >> 6;
  const int wd = wv >> 1, we = wv & 1;
  const int l15 = lane & 15, q = lane >> 4;
  const int sw0 = (q ^ (lane & 7)) * 8;
  const int sw1 = ((4 + q) ^ (lane & 7)) * 8;
  const int lb = (t >> 4) * 4;          // l base within chunk (0..60)
  const int c4 = (t & 15) * 4;          // d/e base

  float ksacc[4] = {0.f, 0.f, 0.f, 0.f};
  f32x4 acc[2][2] = {};

  for (int cc = 0; cc < 4; ++cc) {
    __syncthreads();
    f16x4 pk4[4], vv4[4];
    float w4[4];
#pragma unroll
    for (int lp = 0; lp < 4; ++lp) {
      int lg = l0 + cc * 64 + lb + lp;
      size_t grow = ((size_t)b * L_ + lg) * C_ + h * DH_ + c4;
      pk4[lp] = *(const f16x4*)(phiK + grow);
      vv4[lp] = *(const f16x4*)(Vh + grow);
      w4[lp] = score[(size_t)bh * LK_ + 1 + lg];
    }
#pragma unroll
    for (int j = 0; j < 4; ++j) {
      int d = c4 + j;
      f16x4 pw, vw;
#pragma unroll
      for (int lp = 0; lp < 4; ++lp) {
        float wp = w4[lp] * (float)pk4[lp][j];
        ksacc[j] += wp;
        pw[lp] = (f16)wp;
        vw[lp] = vv4[lp][j];
      }
      int addr = d * 64 + ((((lb >> 3) ^ (d & 7)) << 3) | (lb & 7));
      *(f16x4*)&Pt[addr] = pw;
      *(f16x4*)&Vt[addr] = vw;
    }
    __syncthreads();
#pragma unroll
    for (int ks = 0; ks < 2; ++ks) {
      const int sw = ks ? sw1 : sw0;
      f16x8 af[2], bf[2];
#pragma unroll
      for (int i = 0; i < 2; ++i)
        af[i] = *(const f16x8*)&Pt[(wd * 32 + i * 16 + l15) * 64 + sw];
#pragma unroll
      for (int j = 0; j < 2; ++j)
        bf[j] = *(const f16x8*)&Vt[(we * 32 + j * 16 + l15) * 64 + sw];
#pragma unroll
      for (int i = 0; i < 2; ++i)
#pragma unroll
        for (int j = 0; j < 2; ++j)
          acc[i][j] = __builtin_amdgcn_mfma_f32_16x16x32_f16(af[i], bf[j], acc[i][j], 0, 0, 0);
    }
  }

  __syncthreads();
#pragma unroll
  for (int j = 0; j < 4; ++j) red[t >> 4][c4 + j] = ksacc[j];
  __syncthreads();
  if (t < 64) {
    float s = 0.f;
#pragma unroll
    for (int g = 0; g < 16; ++g) s += red[g][t];
    atomicAdd(&ksum[bh * 64 + t], s);
  }

  float* dst = kvp + ((size_t)bh * 16 + blockIdx.x) * 4096;
#pragma unroll
  for (int i = 0; i < 2; ++i)
#pragma unroll
    for (int j = 0; j < 2; ++j) {
      int d = wd * 32 + i * 16 + q * 4;
      int e = we * 32 + j * 16 + l15;
      *(f32x4*)&dst[e * 64 + d] = acc[i][j];
    }
}

// compact per-head kvT[b][h][e][d] (f16), summing 16 partials.
__global__ __launch_bounds__(256) void build_kvt(const float* __restrict__ kvp,
                                                 f16* __restrict__ kvt) {
  int i = blockIdx.x * 256 + threadIdx.x;
  int bh = i >> 12;
  const float* p = kvp + ((size_t)bh * 16) * 4096 + (i & 4095);
  float v = 0.f;
#pragma unroll
  for (int pp = 0; pp < 16; ++pp) v += p[pp * 4096];
  kvt[i] = (f16)v;
}

// ---------------------------------------------------------------- attention out (+ fused bottom, + zero-token ksum term)
__global__ __launch_bounds__(256, 4) void attn_out(const f16* __restrict__ phiQ,
                                                   const f16* __restrict__ kvt,
                                                   const float* __restrict__ ksum,
                                                   const float* __restrict__ score,
                                                   const float* __restrict__ pk0t,
                                                   f16* __restrict__ Ch) {
  __shared__ f16 smem[12288];
  __shared__ float bots[128];
  const int tid = threadIdx.x;
  const int lane = tid & 63, wv = tid >> 6;
  const int bm = blockIdx.x * 128;
  const int h = blockIdx.y;
  const int b = bm >> 12;
  const int l15 = lane & 15, q = lane >> 4;

  const int srow = tid >> 3;
  const int schunk = (tid & 7) ^ (srow & 7);
  const f16* pa = phiQ + (size_t)(bm + srow) * C_ + h * DH_ + schunk * 8;
  const f16* pb = kvt + ((size_t)(b * H_ + h) * DH_ + srow) * DH_ + schunk * 8;
  f16* la = smem + tid * 8;
  f16* lb = smem + 8192 + tid * 8;
  const int sw0 = (q ^ (lane & 7)) * 8;
  const int sw1 = ((4 + q) ^ (lane & 7)) * 8;

#pragma unroll
  for (int p = 0; p < 4; ++p) gl16(la + p * 2048, pa + (size_t)p * 32 * C_);
#pragma unroll
  for (int p = 0; p < 2; ++p) gl16(lb + p * 2048, pb + (size_t)p * 32 * DH_);
  __syncthreads();

  // bottom: row dot ksum_eff from staged A (swizzled chunk slots)
  {
    int row = tid >> 1, hf = tid & 1;
    float s0 = score[(size_t)(b * H_ + h) * LK_];
    const float* ksh = ksum + ((size_t)(b * H_ + h)) * 64 + hf * 32;
    const float* pkh = pk0t + h * DH_ + hf * 32;
    float bsum = 0.f;
#pragma unroll
    for (int cc = 0; cc < 4; ++cc) {
      int ch = hf * 4 + cc;
      f16x8 vv2 = *(const f16x8*)&smem[row * 64 + ((ch ^ (row & 7)) << 3)];
#pragma unroll
      for (int j = 0; j < 8; ++j)
        bsum += (float)vv2[j] * (ksh[cc * 8 + j] + s0 * pkh[cc * 8 + j]);
    }
    bsum += __shfl_xor(bsum, 1);
    if (hf == 0) bots[row] = bsum;
  }

  f32x4 acc[2][4] = {};
#pragma unroll
  for (int ks = 0; ks < 2; ++ks) {
    const int sw = ks ? sw1 : sw0;
    f16x8 af[2], bf[4];
#pragma unroll
    for (int i = 0; i < 2; ++i)
      af[i] = *(const f16x8*)&smem[(wv * 32 + i * 16 + l15) * 64 + sw];
#pragma unroll
    for (int j = 0; j < 4; ++j)
      bf[j] = *(const f16x8*)&smem[8192 + (j * 16 + l15) * 64 + sw];
#pragma unroll
    for (int i = 0; i < 2; ++i)
#pragma unroll
      for (int j = 0; j < 4; ++j)
        acc[i][j] = __builtin_amdgcn_mfma_f32_16x16x32_f16(af[i], bf[j], acc[i][j], 0, 0, 0);
  }
  __syncthreads();   // MFMA reads done; bots visible to all

#pragma unroll
  for (int j = 0; j < 4; ++j) {
    int lc = j * 16 + l15;
#pragma unroll
    for (int i = 0; i < 2; ++i) {
#pragma unroll
      for (int r = 0; r < 4; ++r) {
        int lr = wv * 32 + i * 16 + q * 4 + r;
        float v = acc[i][j][r] * frcp(bots[lr] + 1e-6f);
        smem[lr * 64 + ((((lc >> 3) ^ (lr & 7)) << 3) | (lc & 7))] = (f16)v;
      }
    }
  }
  __syncthreads();

#pragma unroll
  for (int p = 0; p < 4; ++p) {
    int idx = p * 256 + tid;
    int row = idx >> 3, ch = idx & 7;
    f16x8 vv = *(const f16x8*)&smem[row * 64 + ((ch ^ (row & 7)) << 3)];
    *(f16x8*)&Ch[(size_t)(bm + row) * C_ + h * DH_ + ch * 8] = vv;
  }
}

// ---------------------------------------------------------------- LayerNorm (f16 in/out)
__global__ __launch_bounds__(256) void ln16(const f16* __restrict__ X,
                                            const float* __restrict__ g,
                                            const float* __restrict__ bta,
                                            f16* __restrict__ Y, int threeway) {
  int wv = threadIdx.x >> 6, lane = threadIdx.x & 63;
  int r = blockIdx.x * 4 + wv;
  int token = r, which = 0;
  if (threeway) { token = r / 3; which = r - token * 3; }
  const f16* xr = X + (size_t)r * C_;
  f16x8 v = *(const f16x8*)(xr + lane * 8);
  float vals[8];
  float s = 0.f, s2 = 0.f;
#pragma unroll
  for (int j = 0; j < 8; ++j) { vals[j] = (float)v[j]; s += vals[j]; s2 += vals[j] * vals[j]; }
#pragma unroll
  for (int m_ = 1; m_ < 64; m_ <<= 1) { s += __shfl_xor(s, m_); s2 += __shfl_xor(s2, m_); }
  float mu = s * (1.f / C_);
  float var = s2 * (1.f / C_) - mu * mu;
  float rstd = rsqrtf(var + 1e-5f);
  const float* gp = g + which * C_;
  const float* bp = bta + which * C_;
  f16x8 o;
#pragma unroll
  for (int j = 0; j < 8; ++j) {
    int c = lane * 8 + j;
    o[j] = (f16)((vals[j] - mu) * rstd * gp[c] + bp[c]);
  }
  *(f16x8*)(Y + ((size_t)which * BL_ + token) * C_ + lane * 8) = o;
}

// ---------------------------------------------------------------- q_probe
__global__ __launch_bounds__(256) void qprobe2(const f16* __restrict__ Q,
                                               float* __restrict__ qp) {
  int blk = blockIdx.x;
  int b = blk >> 6;
  int r0 = blk * 64;
  int t = threadIdx.x;
  int c8 = (t & 63) * 8, rg = t >> 6;
  float s[8] = {0.f, 0.f, 0.f, 0.f, 0.f, 0.f, 0.f, 0.f};
#pragma unroll
  for (int i = 0; i < 16; ++i) {
    const f16* row = Q + ((size_t)r0 + rg + i * 4) * C_ + c8;
    f16x8 v = *(const f16x8*)row;
#pragma unroll
    for (int j = 0; j < 8; ++j) s[j] += (float)v[j];
  }
  __shared__ float red[4][520];
#pragma unroll
  for (int j = 0; j < 8; ++j) red[rg][c8 + j] = s[j];
  __syncthreads();
  int c = t * 2;
  float a0 = red[0][c] + red[1][c] + red[2][c] + red[3][c];
  float a1 = red[0][c + 1] + red[1][c + 1] + red[2][c + 1] + red[3][c + 1];
  atomicAdd(&qp[b * C_ + c], a0);
  atomicAdd(&qp[b * C_ + c + 1], a1);
}

// ---------------------------------------------------------------- score logits
__global__ __launch_bounds__(256) void logits_kernel(const f16* __restrict__ Kh,
                                                     const float* __restrict__ qp,
                                                     float* __restrict__ score) {
  int wv = threadIdx.x >> 6, lane = threadIdx.x & 63;
  int token = blockIdx.x * 4 + wv;
  int b = token >> 12;
  int l = token & (L_ - 1);
  const f16* row = Kh + (size_t)token * C_;
  int h = lane >> 3, j0 = (lane & 7) * 8;
  const float* qph = qp + b * C_ + h * DH_ + j0;
  float p = 0.f;
#pragma unroll
  for (int j = 0; j < 8; ++j) p += qph[j] * (float)row[h * DH_ + j0 + j];
  p += __shfl_xor(p, 1); p += __shfl_xor(p, 2); p += __shfl_xor(p, 4);
  if ((lane & 7) == 0)
    score[((size_t)b * H_ + h) * LK_ + 1 + l] = p * (1.f / L_) * 0.125f;
}

__global__ __launch_bounds__(256) void softmax_kernel(float* __restrict__ score) {
  int bh = blockIdx.x, t = threadIdx.x;
  float* s = score + (size_t)bh * LK_;
  __shared__ float red[256];
  float mx = 0.f;
  for (int i = t; i < L_; i += 256) mx = fmaxf(mx, s[1 + i]);
  red[t] = mx; __syncthreads();
  for (int k = 128; k; k >>= 1) { if (t < k) red[t] = fmaxf(red[t], red[t + k]); __syncthreads(); }
  mx = red[0]; __syncthreads();
  float sum = (t == 0) ? expf(-mx) : 0.f;
  for (int i = t; i < L_; i += 256) { float e = expf(s[1 + i] - mx); s[1 + i] = e; sum += e; }
  red[t] = sum; __syncthreads();
  for (int k = 128; k; k >>= 1) { if (t < k) red[t] += red[t + k]; __syncthreads(); }
  float inv = 1.f / red[0];
  __syncthreads();
  for (int i = t; i < L_; i += 256) s[1 + i] *= inv;
  if (t == 0) s[0] = expf(-mx) * inv;
}

// ---------------------------------------------------------------- launch
extern "C" void kernel_launch(void* const* d_in, const int* in_sizes, int n_in,
                              void* d_out, int out_size, void* d_ws, size_t ws_size,
                              hipStream_t stream) {
  (void)in_sizes; (void)n_in; (void)out_size; (void)ws_size;
  const float* x     = (const float*)d_in[0];
  const float* Wq    = (const float*)d_in[1];
  const float* bq    = (const float*)d_in[2];
  const float* gq    = (const float*)d_in[3];
  const float* betaq = (const float*)d_in[4];
  const float* Wk    = (const float*)d_in[5];
  const float* bk    = (const float*)d_in[6];
  const float* gk    = (const float*)d_in[7];
  const float* betak = (const float*)d_in[8];
  const float* Wv    = (const float*)d_in[9];
  const float* bv    = (const float*)d_in[10];
  const float* gv    = (const float*)d_in[11];
  const float* betav = (const float*)d_in[12];
  const float* Wkq   = (const float*)d_in[13];
  const float* bkq   = (const float*)d_in[14];
  const float* Wkk   = (const float*)d_in[15];
  const float* bkk   = (const float*)d_in[16];
  const float* g_at  = (const float*)d_in[17];
  const float* b_at  = (const float*)d_in[18];
  const float* W1    = (const float*)d_in[19];
  const float* b1    = (const float*)d_in[20];
  const float* W2    = (const float*)d_in[21];
  const float* b2    = (const float*)d_in[22];
  float* out = (float*)d_out;

  char* ws = (char*)d_ws;
  size_t off = 0;
  auto alloc = [&](size_t bytes) -> void* {
    void* p = ws + off;
    off += (bytes + 255) & ~(size_t)255;
    return p;
  };
  f16* U1    = (f16*)alloc((size_t)BL_ * MLP_ * 2);       // 64 MB
  f16* QKVh  = (f16*)alloc((size_t)3 * BL_ * C_ * 2);     // 48 MB
  f16* phiQK = (f16*)alloc((size_t)2 * BL_ * C_ * 2);     // 32 MB
  f16* xf    = (f16*)alloc((size_t)BL_ * C_ * 2);         // 16 MB
  f16* WqkvT = (f16*)alloc((size_t)3 * C_ * C_ * 2);
  f16* WkqT  = (f16*)alloc((size_t)C_ * C_ * 2);
  f16* WkkT  = (f16*)alloc((size_t)C_ * C_ * 2);
  f16* W1T   = (f16*)alloc((size_t)C_ * MLP_ * 2);
  f16* W2T   = (f16*)alloc((size_t)MLP_ * C_ * 2);
  f16* kvt   = (f16*)alloc((size_t)B_ * H_ * DH_ * DH_ * 2);
  float* qp    = (float*)alloc((size_t)B_ * C_ * 4);          // \ one memset
  float* ksum  = (float*)alloc((size_t)B_ * H_ * DH_ * 4);    // / (adjacent)
  float* score = (float*)alloc((size_t)B_ * H_ * LK_ * 4);
  float* kvp   = (float*)alloc((size_t)B_ * H_ * 16 * 4096 * 4);
  float* bqkv    = (float*)alloc(1536 * 4);
  float* gqkv    = (float*)alloc(1536 * 4);
  float* betaqkv = (float*)alloc(1536 * 4);
  float* bphi    = (float*)alloc(1024 * 4);
  float* pk0t    = (float*)alloc(512 * 4);

  f16* tmpqkv = U1;
  f16* tmpA   = U1;
  f16* h1     = U1;
  f16* Qh = QKVh;
  f16* Kh = QKVh + (size_t)BL_ * C_;
  f16* Vh = QKVh + (size_t)2 * BL_ * C_;
  f16* ah = QKVh;
  f16* phiQ = phiQK;
  f16* phiK = phiQK + (size_t)BL_ * C_;

  dim3 blk(256);
  dim3 blk512(512);

  pack_params<<<6, blk, 0, stream>>>(bq, bk, bv, gq, gk, gv, betaq, betak, betav,
                                     bkq, bkk, bqkv, gqkv, betaqkv, bphi, pk0t);

  transpose_w5<<<dim3(16, 16, 5), blk, 0, stream>>>(Wq, Wk, Wv, Wkq, Wkk, WqkvT);
  transpose_w12<<<dim3(64, 16, 2), blk, 0, stream>>>(W1, W2, W1T, W2T);

  transpose_x<<<dim3(L_ / 32, C_ / 32, B_), blk, 0, stream>>>(x, xf);

  // fused QKV projection (256^2 counted-vmcnt + setprio)
  gemm256<5><<<dim3(BL_ / 256, 1536 / 256), blk512, 0, stream>>>(
      xf, WqkvT, bqkv, tmpqkv, 1536, C_, 0, 0, 0, 0);
  ln16<<<3 * BL_ / 4, blk, 0, stream>>>(tmpqkv, gqkv, betaqkv, QKVh, 1);

  // zero qp + ksum in one shot (adjacent allocations)
  hipMemsetAsync(qp, 0, (size_t)(B_ * C_ + B_ * H_ * DH_) * 4, stream);
  qprobe2<<<BL_ / 64, blk, 0, stream>>>(Qh, qp);

  // phi projections (m97-sbuf 128^2; grid = (N-tiles, M-tiles, z))
  gemm128s<1><<<dim3(C_ / 128, BL_ / 128, 2), blk, 0, stream>>>(
      Qh, WkqT, bphi, phiQ, C_, C_,
      (long long)BL_ * C_, (long long)C_ * C_, (long long)BL_ * C_, (long long)C_);

  logits_kernel<<<BL_ / 4, blk, 0, stream>>>(Kh, qp, score);
  softmax_kernel<<<B_ * H_, blk, 0, stream>>>(score);

  // kv partials + ksum via MFMA
  kv_mfma<<<dim3(16, B_ * H_), blk, 0, stream>>>(phiK, Vh, score, kvp, ksum);
  build_kvt<<<(B_ * H_ * DH_ * DH_) / 256, blk, 0, stream>>>(kvp, kvt);

  // attention out (bottom + zero-token ksum term fused)
  attn_out<<<dim3(BL_ / 128, H_), blk, 0, stream>>>(phiQ, kvt, ksum, score, pk0t, tmpA);

  ln16<<<BL_ / 4, blk, 0, stream>>>(tmpA, g_at, b_at, ah, 0);

  // MLP up (m97-sbuf 128^2; grid = (N-tiles, M-tiles))
  gemm128s<2><<<dim3(MLP_ / 128, BL_ / 128), blk, 0, stream>>>(
      ah, W1T, b1, h1, MLP_, C_, 0, 0, 0, 0);
  // MLP down fused with residual-add + transpose + x-add -> out (512-thr dbuf)
  gemm512d6<<<dim3(BL_ / 128, C_ / 128), blk512, 0, stream>>>(
      h1, W2T, b2, C_, MLP_, ah, x, out);
}